// Round 6
// baseline (423.585 us; speedup 1.0000x reference)
//
#include <hip/hip_runtime.h>

// TT-layer y = (c0 x c1 x c2 x c3) . x + bias, B=8192, all dims 8, ranks 16.
//
// Factorization: precompute (per launch, into d_ws, fp32->bf16):
//   CC [n1][q=(n2*16+r2)][p=(m1*8+m2)]   = sum_r1 c0[n1][m1][r1]*c1[r1][n2][m2][r2]   (8x128x64)
//   C23[row=(n3*8+n4)][s~(r2,m3,m4)]     = sum_r3 c2[r2][n3][m3][r3]*c3[r3][n4][m4]   (64x1024)
// Main kernel, 2 batch elems / block, per n1:
//   stage01: D1[q][(b',u)] = CC_n1 * xt      (M=128,N=128,K=64)  -> scatter to t2t
//   stage2 : y[row][(b',n2)] = C23 * t2t     (M=64, N=16, K=1024) -> +bias -> out
//
// This version: stage2 is K-SPLIT across the 4 waves (wave w takes K-slice
// [256w,256w+256) of ALL 64 rows) so t2t is read from LDS exactly ONCE per
// block instead of 4x (each b128 B-frag feeds 4 MFMAs). Cross-wave partial
// sums exchanged through a 12 KB LDS psum buffer (each wave keeps its own
// row-tile rt==w, writes the 3 foreign tiles). Two barriers per n1.
// f2bf packing kept pure-C++ (a v_cvt_pk_bf16_f32 inline-asm variant NaN'd).

typedef __attribute__((ext_vector_type(8))) short bf16x8;
typedef __attribute__((ext_vector_type(4))) float f32x4;

__device__ __forceinline__ short f2bf(float f) {
    union { float f; unsigned u; } v; v.f = f;
    unsigned u = v.u;
    u += 0x7fffu + ((u >> 16) & 1u);   // round-to-nearest-even
    return (short)(u >> 16);
}

// ---------------- precompute kernel: build CC and C23 in d_ws ----------------
__global__ void tt_pre(const float* __restrict__ c0, const float* __restrict__ c1,
                       const float* __restrict__ c2, const float* __restrict__ c3,
                       short* __restrict__ ws) {
    int id = blockIdx.x * 256 + threadIdx.x;     // 0 .. 131071
    if (id < 65536) {
        // CC: id = n1*8192 + q*64 + p
        int p  = id & 63, q = (id >> 6) & 127, n1 = id >> 13;
        int m1 = p >> 3, m2 = p & 7, n2 = q >> 4, r2 = q & 15;
        float s = 0.f;
        #pragma unroll
        for (int r1 = 0; r1 < 16; ++r1)
            s += c0[(n1 * 8 + m1) * 16 + r1] * c1[((r1 * 8 + n2) * 8 + m2) * 16 + r2];
        ws[id] = f2bf(s);
    } else {
        // C23: id2 = row*1024 + s_, row=(n3*8+n4)
        int id2 = id - 65536;
        int s_  = id2 & 1023, row = id2 >> 10;
        int n3 = row >> 3, n4 = row & 7;
        int m3 = s_ >> 7, m4 = (s_ >> 4) & 7, r2s = s_ & 15;
        int r2 = (r2s - 4 * (m3 & 1)) & 15;      // inverse of scatter swizzle
        float s = 0.f;
        #pragma unroll
        for (int r3 = 0; r3 < 16; ++r3)
            s += c2[((r2 * 8 + n3) * 8 + m3) * 16 + r3] * c3[(r3 * 8 + n4) * 8 + m4];
        ws[65536 + id2] = f2bf(s);
    }
}

// ---------------- main kernel ----------------
#define XT_S 72      // xt row stride (shorts): 144B, 16B-aligned, +4 banks/row
#define T2_S 1032    // t2t row stride (shorts): 2064B, 16B-aligned, +4 banks/row

__global__ __launch_bounds__(256, 2) void tt_main(
    const float* __restrict__ x, const short* __restrict__ ws,
    const float* __restrict__ bias, float* __restrict__ out)
{
    __shared__ short t2t[16 * T2_S];     // 33024 B; xt (18432 B) overlays front
    __shared__ float psum[3072];         // 12288 B: [w][slot 0..2][lane] f32x4

    const short* cc  = ws;               // [8][128][64]
    const short* c23 = ws + 65536;       // [64][1024]

    const int t = threadIdx.x, w = t >> 6, L = t & 63;
    const int quad = L >> 4, l16 = L & 15;
    const long long b0 = (long long)blockIdx.x * 2;
    const int mh = w >> 1, nh = w & 1;

    short* xt = t2t;                     // overlay: dead after b01 load (B1b)

    // ---- build xt (bf16, transposed): wave w -> b'=w>>1, p-range (w&1)*32..+31, u=L
    {
        const float* xb = x + (b0 + (w >> 1)) * 4096;
        const int pr = (w & 1) * 32;
        short* dst = &xt[(((w >> 1) * 64 + L) * XT_S) + pr];
        #pragma unroll
        for (int g = 0; g < 4; ++g) {
            bf16x8 v;
            #pragma unroll
            for (int j = 0; j < 8; ++j) v[j] = f2bf(xb[(pr + g * 8 + j) * 64 + L]);
            *(bf16x8*)(dst + g * 8) = v;
        }
    }

    // ---- persistent A2 frags (C23), K-split: wave w -> ALL 64 rows, K-slice
    //      [256w, 256w+256). a2[rt*8+kt] covers rows rt*16.., k = w*256+kt*32.
    bf16x8 a2[32];
    {
        const short* base = c23 + l16 * 1024 + w * 256 + quad * 8;
        #pragma unroll
        for (int rt = 0; rt < 4; ++rt)
            #pragma unroll
            for (int kt = 0; kt < 8; ++kt)
                a2[rt * 8 + kt] = *(const bf16x8*)(base + rt * 16 * 1024 + kt * 32);
    }

    // ---- a1 prefetch (h=0 half of stage01 A): latency hides under stage2
    bf16x8 a1pf[4];
    auto pfload = [&](int n1) {
        const short* ab = cc + n1 * 8192 + (mh * 64 + l16) * 64 + quad * 8;
        a1pf[0] = *(const bf16x8*)(ab);              // kt=0, mt2=0
        a1pf[1] = *(const bf16x8*)(ab + 1024);       // kt=0, mt2=1
        a1pf[2] = *(const bf16x8*)(ab + 32);         // kt=1, mt2=0
        a1pf[3] = *(const bf16x8*)(ab + 1024 + 32);  // kt=1, mt2=1
    };
    pfload(0);

    __syncthreads();                     // B1: xt complete

    // ---- persistent B01 frags (x): wave -> (mh, nh); nh picks b'
    bf16x8 b01[8];                       // [kt*4+nt]
    #pragma unroll
    for (int kt = 0; kt < 2; ++kt)
        #pragma unroll
        for (int nt = 0; nt < 4; ++nt)
            b01[kt * 4 + nt] =
                *(const bf16x8*)&xt[(nh * 64 + nt * 16 + l16) * XT_S + kt * 32 + quad * 8];

    __syncthreads();                     // B1b: b01 reads done before xt overwritten

    // ---- stage01 + scatter for one n1 (h=0 uses prefetched a1, h=1 loads fresh)
    auto stage01 = [&](int n1) {
        #pragma unroll
        for (int h = 0; h < 2; ++h) {
            bf16x8 a1[4];
            if (h == 0) {
                a1[0] = a1pf[0]; a1[1] = a1pf[1]; a1[2] = a1pf[2]; a1[3] = a1pf[3];
            } else {
                const short* ab = cc + n1 * 8192 + (mh * 64 + 32 + l16) * 64 + quad * 8;
                a1[0] = *(const bf16x8*)(ab);
                a1[1] = *(const bf16x8*)(ab + 1024);
                a1[2] = *(const bf16x8*)(ab + 32);
                a1[3] = *(const bf16x8*)(ab + 1024 + 32);
            }
            f32x4 acc[2][4] = {};
            #pragma unroll
            for (int mt2 = 0; mt2 < 2; ++mt2)
                #pragma unroll
                for (int nt = 0; nt < 4; ++nt) {
                    acc[mt2][nt] = __builtin_amdgcn_mfma_f32_16x16x32_bf16(
                        a1[mt2], b01[nt], acc[mt2][nt], 0, 0, 0);
                    acc[mt2][nt] = __builtin_amdgcn_mfma_f32_16x16x32_bf16(
                        a1[2 + mt2], b01[4 + nt], acc[mt2][nt], 0, 0, 0);
                }
            // scatter (b64 stores, swizzled s keeps i=0..3 contiguous)
            #pragma unroll
            for (int mt2 = 0; mt2 < 2; ++mt2) {
                const int n2 = mh * 4 + h * 2 + mt2;
                #pragma unroll
                for (int nt = 0; nt < 4; ++nt) {
                    const int u  = nt * 16 + l16;        // 0..63
                    const int m3 = u >> 3, m4 = u & 7;
                    const int rblk = (quad * 4 + 4 * (m3 & 1)) & 15;
                    int2 pk;
                    pk.x = (int)((unsigned short)f2bf(acc[mt2][nt][0]) |
                                 ((unsigned)(unsigned short)f2bf(acc[mt2][nt][1]) << 16));
                    pk.y = (int)((unsigned short)f2bf(acc[mt2][nt][2]) |
                                 ((unsigned)(unsigned short)f2bf(acc[mt2][nt][3]) << 16));
                    *(int2*)&t2t[(nh * 8 + n2) * T2_S + (m3 * 8 + m4) * 16 + rblk] = pk;
                }
            }
        }
    };

    stage01(0);                          // fill t2t with n1=0
    __syncthreads();                     // A(0): t2t ready

    #pragma unroll 1
    for (int k = 0; k < 8; ++k) {
        if (k < 7) pfload(k + 1);        // a1(k+1); drains at barrier B (covered)

        // ==== stage2 partial: d[rt] = C23[rt-rows][K-slice w] * t2t[K-slice w]
        f32x4 d[4] = {};
        f32x4 down;                      // own row-tile partial (rt == w)
        {
            const short* tb = &t2t[l16 * T2_S + w * 256 + quad * 8];
            __builtin_amdgcn_s_setprio(1);
            #pragma unroll
            for (int kt = 0; kt < 8; ++kt) {
                bf16x8 bf = *(const bf16x8*)(tb + kt * 32);
                #pragma unroll
                for (int rt = 0; rt < 4; ++rt)
                    d[rt] = __builtin_amdgcn_mfma_f32_16x16x32_bf16(
                        a2[rt * 8 + kt], bf, d[rt], 0, 0, 0);
            }
            __builtin_amdgcn_s_setprio(0);
        }
        // ---- psum exchange: keep own tile, write 3 foreign tiles
        #pragma unroll
        for (int rt = 0; rt < 4; ++rt) {
            if (rt == w) {
                down = d[rt];
            } else {
                const int s = rt - (rt > w ? 1 : 0);
                *(f32x4*)&psum[((w * 3 + s) * 64 + L) * 4] = d[rt];
            }
        }
        __syncthreads();                 // B: psums ready, t2t fully consumed

        // ---- final reduce (rows 16w + quad*4 + i, col l16) + bias + store
        {
            #pragma unroll
            for (int w2 = 0; w2 < 4; ++w2) {
                if (w2 != w) {
                    const int s = w - (w > w2 ? 1 : 0);
                    f32x4 p = *(const f32x4*)&psum[((w2 * 3 + s) * 64 + L) * 4];
                    down[0] += p[0]; down[1] += p[1];
                    down[2] += p[2]; down[3] += p[3];
                }
            }
            const int bp = l16 >> 3, n2 = l16 & 7;
            const int off = k * 512 + n2 * 64 + 16 * w + quad * 4;
            const float4 bv = *(const float4*)(bias + off);
            float4 ov;
            ov.x = down[0] + bv.x;
            ov.y = down[1] + bv.y;
            ov.z = down[2] + bv.z;
            ov.w = down[3] + bv.w;
            *(float4*)(out + (b0 + bp) * 4096 + off) = ov;
        }

        // ==== stage01(k+1) into t2t (consumed at B), then barrier A(k+1)
        if (k < 7) {
            stage01(k + 1);
            __syncthreads();             // A: t2t(k+1) ready; psum reads done
        }
    }
}

extern "C" void kernel_launch(void* const* d_in, const int* in_sizes, int n_in,
                              void* d_out, int out_size, void* d_ws, size_t ws_size,
                              hipStream_t stream) {
    const float* x    = (const float*)d_in[0];
    const float* c0   = (const float*)d_in[1];
    const float* c1   = (const float*)d_in[2];
    const float* c2   = (const float*)d_in[3];
    const float* c3   = (const float*)d_in[4];
    const float* bias = (const float*)d_in[5];
    float* out = (float*)d_out;
    short* ws  = (short*)d_ws;           // 256 KB used: CC (128K) + C23 (128K)

    hipLaunchKernelGGL(tt_pre, dim3(512), dim3(256), 0, stream, c0, c1, c2, c3, ws);
    hipLaunchKernelGGL(tt_main, dim3(4096), dim3(256), 0, stream, x, ws, bias, out);
}

// Round 7
// 410.581 us; speedup vs baseline: 1.0317x; 1.0317x over previous
//
#include <hip/hip_runtime.h>
#include <hip/hip_bf16.h>

// TT-layer y = (c0 x c1 x c2 x c3) . x + bias, B=8192, all dims 8, ranks 16.
//
// Factorization: precompute (per launch, into d_ws, fp32->bf16):
//   CC [n1][q=(n2*16+r2)][p=(m1*8+m2)]   = sum_r1 c0[n1][m1][r1]*c1[r1][n2][m2][r2]   (8x128x64)
//   C23[row=(n3*8+n4)][s~(r2,m3,m4)]     = sum_r3 c2[r2][n3][m3][r3]*c3[r3][n4][m4]   (64x1024)
// Main kernel, 2 batch elems / block, per n1:
//   stage01: D1[q][(b',u)] = CC_n1 * xt      (M=128,N=128,K=64)  -> scatter to t2t
//   stage2 : y[row][(b',n2)] = C23 * t2t     (M=64, N=16, K=1024) -> +bias -> out
//
// v7: ONE barrier per n1. stage2 split 2-way rows x 2-way K across the 4
// waves (wave w: rh=w>>1 rows [32rh,+32), kh=w&1 K [512kh,+512)); partner
// waves exchange one 16x16 f32 tile through a tiny double-buffered psum
// (8 KB). t2t double-buffered (66 KB) so stage01(k+1) runs back-to-back with
// stage2(k) in a single barrier-free phase (ILP + latency overlap); epilogue
// (psum read + bias + store) after the barrier. bf16 packing via
// __float22bfloat162_rn (compiler-safe v_cvt_pk_bf16_f32; the inline-asm
// variant NaN'd in an earlier round).

typedef __attribute__((ext_vector_type(8))) short bf16x8;
typedef __attribute__((ext_vector_type(4))) float f32x4;

__device__ __forceinline__ short f2bf(float f) {
    union { float f; unsigned u; } v; v.f = f;
    unsigned u = v.u;
    u += 0x7fffu + ((u >> 16) & 1u);   // round-to-nearest-even
    return (short)(u >> 16);
}

__device__ __forceinline__ int pk2bf(float lo, float hi) {   // RNE packed
    union { __hip_bfloat162 h; int i; } u;
    u.h = __float22bfloat162_rn(make_float2(lo, hi));
    return u.i;
}

// ---------------- precompute kernel: build CC and C23 in d_ws ----------------
__global__ void tt_pre(const float* __restrict__ c0, const float* __restrict__ c1,
                       const float* __restrict__ c2, const float* __restrict__ c3,
                       short* __restrict__ ws) {
    int id = blockIdx.x * 256 + threadIdx.x;     // 0 .. 131071
    if (id < 65536) {
        // CC: id = n1*8192 + q*64 + p
        int p  = id & 63, q = (id >> 6) & 127, n1 = id >> 13;
        int m1 = p >> 3, m2 = p & 7, n2 = q >> 4, r2 = q & 15;
        float s = 0.f;
        #pragma unroll
        for (int r1 = 0; r1 < 16; ++r1)
            s += c0[(n1 * 8 + m1) * 16 + r1] * c1[((r1 * 8 + n2) * 8 + m2) * 16 + r2];
        ws[id] = f2bf(s);
    } else {
        // C23: id2 = row*1024 + s_, row=(n3*8+n4)
        int id2 = id - 65536;
        int s_  = id2 & 1023, row = id2 >> 10;
        int n3 = row >> 3, n4 = row & 7;
        int m3 = s_ >> 7, m4 = (s_ >> 4) & 7, r2s = s_ & 15;
        int r2 = (r2s - 4 * (m3 & 1)) & 15;      // inverse of scatter swizzle
        float s = 0.f;
        #pragma unroll
        for (int r3 = 0; r3 < 16; ++r3)
            s += c2[((r2 * 8 + n3) * 8 + m3) * 16 + r3] * c3[(r3 * 8 + n4) * 8 + m4];
        ws[65536 + id2] = f2bf(s);
    }
}

// ---------------- main kernel ----------------
#define XT_S 72      // xt row stride (shorts): 144B, 16B-aligned, +4 banks/row
#define T2_S 1032    // t2t row stride (shorts): 2064B, 16B-aligned, +4 banks/row
#define BUFSH (16 * T2_S)

__global__ __launch_bounds__(256, 2) void tt_main(
    const float* __restrict__ x, const short* __restrict__ ws,
    const float* __restrict__ bias, float* __restrict__ out)
{
    __shared__ short t2t[2 * BUFSH];     // 66048 B, double-buffered; xt overlays buf0
    __shared__ float psum[2][1024];      // 8192 B: [par][slot(0..3)*256 + L*4 + i]

    const short* cc  = ws;               // [8][128][64]
    const short* c23 = ws + 65536;       // [64][1024]

    const int t = threadIdx.x, w = t >> 6, L = t & 63;
    const int quad = L >> 4, l16 = L & 15;
    const long long b0 = (long long)blockIdx.x * 2;
    const int rh = w >> 1, kh = w & 1;   // stage2 roles; stage01 uses same bits
                                         // (mh==rh picks q-half / row-half,
                                         //  nh==kh picks b' / K-half)

    short* xt = t2t;                     // overlay on buf0: dead after b01 load

    // ---- build xt (bf16, transposed): wave -> b'=rh, p-range kh*32..+31, u=L
    {
        const float* xb = x + (b0 + rh) * 4096;
        const int pr = kh * 32;
        short* dst = &xt[((rh * 64 + L) * XT_S) + pr];
        #pragma unroll
        for (int g = 0; g < 4; ++g) {
            float f[8];
            #pragma unroll
            for (int j = 0; j < 8; ++j) f[j] = xb[(pr + g * 8 + j) * 64 + L];
            int4 pk;
            pk.x = pk2bf(f[0], f[1]); pk.y = pk2bf(f[2], f[3]);
            pk.z = pk2bf(f[4], f[5]); pk.w = pk2bf(f[6], f[7]);
            *(int4*)(dst + g * 8) = pk;
        }
    }

    // ---- persistent A2 frags (C23): wave (rh,kh) -> rows [32rh,32rh+32),
    //      K-slice [512kh, 512kh+512). a2[rt*16+kt]: row 32rh+16rt+l16,
    //      k = 512kh + kt*32 + quad*8.
    bf16x8 a2[32];
    {
        const short* base = c23 + (32 * rh + l16) * 1024 + 512 * kh + quad * 8;
        #pragma unroll
        for (int rt = 0; rt < 2; ++rt)
            #pragma unroll
            for (int kt = 0; kt < 16; ++kt)
                a2[rt * 16 + kt] = *(const bf16x8*)(base + rt * 16 * 1024 + kt * 32);
    }

    // ---- a1 prefetch (h=0 half of stage01 A): latency hides under stage2
    bf16x8 a1pf[4];
    auto pfload = [&](int n1) {
        const short* ab = cc + n1 * 8192 + (rh * 64 + l16) * 64 + quad * 8;
        a1pf[0] = *(const bf16x8*)(ab);              // kt=0, mt2=0
        a1pf[1] = *(const bf16x8*)(ab + 1024);       // kt=0, mt2=1
        a1pf[2] = *(const bf16x8*)(ab + 32);         // kt=1, mt2=0
        a1pf[3] = *(const bf16x8*)(ab + 1024 + 32);  // kt=1, mt2=1
    };
    pfload(0);

    __syncthreads();                     // B1: xt complete

    // ---- persistent B01 frags (x): wave -> (rh, kh); kh picks b'
    bf16x8 b01[8];                       // [kt*4+nt]
    #pragma unroll
    for (int kt = 0; kt < 2; ++kt)
        #pragma unroll
        for (int nt = 0; nt < 4; ++nt)
            b01[kt * 4 + nt] =
                *(const bf16x8*)&xt[(kh * 64 + nt * 16 + l16) * XT_S + kt * 32 + quad * 8];

    __syncthreads();                     // B1b: b01 reads done before xt overwritten

    // ---- stage01 + scatter for one n1 into dstbuf
    auto stage01 = [&](int n1, short* dstbuf) {
        #pragma unroll
        for (int h = 0; h < 2; ++h) {
            bf16x8 a1[4];
            if (h == 0) {
                a1[0] = a1pf[0]; a1[1] = a1pf[1]; a1[2] = a1pf[2]; a1[3] = a1pf[3];
            } else {
                const short* ab = cc + n1 * 8192 + (rh * 64 + 32 + l16) * 64 + quad * 8;
                a1[0] = *(const bf16x8*)(ab);
                a1[1] = *(const bf16x8*)(ab + 1024);
                a1[2] = *(const bf16x8*)(ab + 32);
                a1[3] = *(const bf16x8*)(ab + 1024 + 32);
            }
            f32x4 acc[2][4] = {};
            #pragma unroll
            for (int mt2 = 0; mt2 < 2; ++mt2)
                #pragma unroll
                for (int nt = 0; nt < 4; ++nt) {
                    acc[mt2][nt] = __builtin_amdgcn_mfma_f32_16x16x32_bf16(
                        a1[mt2], b01[nt], acc[mt2][nt], 0, 0, 0);
                    acc[mt2][nt] = __builtin_amdgcn_mfma_f32_16x16x32_bf16(
                        a1[2 + mt2], b01[4 + nt], acc[mt2][nt], 0, 0, 0);
                }
            // scatter (b64 stores, swizzled s keeps i=0..3 contiguous)
            #pragma unroll
            for (int mt2 = 0; mt2 < 2; ++mt2) {
                const int n2 = rh * 4 + h * 2 + mt2;
                #pragma unroll
                for (int nt = 0; nt < 4; ++nt) {
                    const int u  = nt * 16 + l16;        // 0..63
                    const int m3 = u >> 3, m4 = u & 7;
                    const int rblk = (quad * 4 + 4 * (m3 & 1)) & 15;
                    int2 pk;
                    pk.x = pk2bf(acc[mt2][nt][0], acc[mt2][nt][1]);
                    pk.y = pk2bf(acc[mt2][nt][2], acc[mt2][nt][3]);
                    *(int2*)&dstbuf[(kh * 8 + n2) * T2_S + (m3 * 8 + m4) * 16 + rblk] = pk;
                }
            }
        }
    };

    stage01(0, t2t);                     // fill buf0 with n1=0 (after B1b: safe)
    __syncthreads();                     // A0: buf0 ready

    #pragma unroll 1
    for (int k = 0; k < 8; ++k) {
        const int p = k & 1;
        if (k < 7) pfload(k + 1);        // a1(k+1) h=0; overlaps stage2 MFMAs

        // ==== stage2(k): d = C23[rows rh][K-half kh] * t2t[p], 4 chains =======
        f32x4 d2[4] = {};                // [rt*2 + (kt&1)]
        {
            const short* tb = &t2t[p * BUFSH + l16 * T2_S + kh * 512 + quad * 8];
            __builtin_amdgcn_s_setprio(1);
            #pragma unroll
            for (int kt = 0; kt < 16; kt += 2) {
                bf16x8 bf0 = *(const bf16x8*)(tb + kt * 32);
                bf16x8 bf1 = *(const bf16x8*)(tb + kt * 32 + 32);
                d2[0] = __builtin_amdgcn_mfma_f32_16x16x32_bf16(a2[kt],          bf0, d2[0], 0, 0, 0);
                d2[1] = __builtin_amdgcn_mfma_f32_16x16x32_bf16(a2[kt + 1],      bf1, d2[1], 0, 0, 0);
                d2[2] = __builtin_amdgcn_mfma_f32_16x16x32_bf16(a2[16 + kt],     bf0, d2[2], 0, 0, 0);
                d2[3] = __builtin_amdgcn_mfma_f32_16x16x32_bf16(a2[16 + kt + 1], bf1, d2[3], 0, 0, 0);
            }
            __builtin_amdgcn_s_setprio(0);
        }
        // own tile rt==kh (rows 16w), foreign rt==1-kh -> partner's slot
        f32x4 down, dfor;
        {
            f32x4 dt0, dt1;
            #pragma unroll
            for (int i = 0; i < 4; ++i) { dt0[i] = d2[0][i] + d2[1][i];
                                          dt1[i] = d2[2][i] + d2[3][i]; }
            if (kh == 0) { down = dt0; dfor = dt1; }
            else         { down = dt1; dfor = dt0; }
        }
        *(f32x4*)&psum[p][(rh * 2 + (1 - kh)) * 256 + L * 4] = dfor;

        // ==== stage01(k+1) into the other buffer (same barrier-free phase) ====
        if (k < 7) stage01(k + 1, t2t + ((k + 1) & 1) * BUFSH);

        __syncthreads();                 // the ONE barrier per n1:
                                         // t2t(k+1) ready; psum(k) ready

        // ==== epilogue(k): add partner partial + bias, store ==================
        {
            f32x4 pp = *(const f32x4*)&psum[p][(rh * 2 + kh) * 256 + L * 4];
            const int bp = l16 >> 3, n2 = l16 & 7;
            const int off = k * 512 + n2 * 64 + 16 * w + quad * 4;
            const float4 bv = *(const float4*)(bias + off);
            float4 ov;
            ov.x = down[0] + pp[0] + bv.x;
            ov.y = down[1] + pp[1] + bv.y;
            ov.z = down[2] + pp[2] + bv.z;
            ov.w = down[3] + pp[3] + bv.w;
            *(float4*)(out + (b0 + bp) * 4096 + off) = ov;
        }
    }
}

extern "C" void kernel_launch(void* const* d_in, const int* in_sizes, int n_in,
                              void* d_out, int out_size, void* d_ws, size_t ws_size,
                              hipStream_t stream) {
    const float* x    = (const float*)d_in[0];
    const float* c0   = (const float*)d_in[1];
    const float* c1   = (const float*)d_in[2];
    const float* c2   = (const float*)d_in[3];
    const float* c3   = (const float*)d_in[4];
    const float* bias = (const float*)d_in[5];
    float* out = (float*)d_out;
    short* ws  = (short*)d_ws;           // 256 KB used: CC (128K) + C23 (128K)

    hipLaunchKernelGGL(tt_pre, dim3(512), dim3(256), 0, stream, c0, c1, c2, c3, ws);
    hipLaunchKernelGGL(tt_main, dim3(4096), dim3(256), 0, stream, x, ws, bias, out);
}

// Round 8
// 400.460 us; speedup vs baseline: 1.0577x; 1.0253x over previous
//
#include <hip/hip_runtime.h>
#include <hip/hip_bf16.h>

// TT-layer y = (c0 x c1 x c2 x c3) . x + bias, B=8192, all dims 8, ranks 16.
//
// Factorization: precompute (per launch, into d_ws, fp32->bf16):
//   CC [n1][q=(n2*16+r2)][p=(m1*8+m2)]   = sum_r1 c0[n1][m1][r1]*c1[r1][n2][m2][r2]   (8x128x64)
//   C23[row=(n3*8+n4)][s~(r2,m3,m4)]     = sum_r3 c2[r2][n3][m3][r3]*c3[r3][n4][m4]   (64x1024)
// Main kernel, 2 batch elems / block, per n1:
//   stage01: D1[q][(b',u)] = CC_n1 * xt      (M=128,N=128,K=64)  -> scatter to t2t
//   stage2 : y[row][(b',n2)] = C23 * t2t     (M=64, N=16, K=1024) -> +bias -> out
//
// v8: n1 processed in PAIRS to double in-region ILP at 2 waves/SIMD
// (occupancy is hard-walled: a2 = C23/4waves/64lanes = 128 regs, LDS 74 KB).
// Region REven = {S2(j), S2(j+1)} (independent MFMA+ds_read streams),
// region ROdd = {epi(j), epi(j+1), S01(j+2), S01(j+3)} (independent
// global-load+MFMA+scatter streams). Same barrier count as v7 (2 per 2 n1),
// same LDS (2 t2t buffers: even n1 -> buf0, odd -> buf1; psum[2] parity
// slots unchanged). a1pf regs reused consume->refill->consume.
// bf16 packing via __float22bfloat162_rn (inline-asm variant NaN'd).

typedef __attribute__((ext_vector_type(8))) short bf16x8;
typedef __attribute__((ext_vector_type(4))) float f32x4;

__device__ __forceinline__ short f2bf(float f) {
    union { float f; unsigned u; } v; v.f = f;
    unsigned u = v.u;
    u += 0x7fffu + ((u >> 16) & 1u);   // round-to-nearest-even
    return (short)(u >> 16);
}

__device__ __forceinline__ int pk2bf(float lo, float hi) {   // RNE packed
    union { __hip_bfloat162 h; int i; } u;
    u.h = __float22bfloat162_rn(make_float2(lo, hi));
    return u.i;
}

// ---------------- precompute kernel: build CC and C23 in d_ws ----------------
__global__ void tt_pre(const float* __restrict__ c0, const float* __restrict__ c1,
                       const float* __restrict__ c2, const float* __restrict__ c3,
                       short* __restrict__ ws) {
    int id = blockIdx.x * 256 + threadIdx.x;     // 0 .. 131071
    if (id < 65536) {
        // CC: id = n1*8192 + q*64 + p
        int p  = id & 63, q = (id >> 6) & 127, n1 = id >> 13;
        int m1 = p >> 3, m2 = p & 7, n2 = q >> 4, r2 = q & 15;
        float s = 0.f;
        #pragma unroll
        for (int r1 = 0; r1 < 16; ++r1)
            s += c0[(n1 * 8 + m1) * 16 + r1] * c1[((r1 * 8 + n2) * 8 + m2) * 16 + r2];
        ws[id] = f2bf(s);
    } else {
        // C23: id2 = row*1024 + s_, row=(n3*8+n4)
        int id2 = id - 65536;
        int s_  = id2 & 1023, row = id2 >> 10;
        int n3 = row >> 3, n4 = row & 7;
        int m3 = s_ >> 7, m4 = (s_ >> 4) & 7, r2s = s_ & 15;
        int r2 = (r2s - 4 * (m3 & 1)) & 15;      // inverse of scatter swizzle
        float s = 0.f;
        #pragma unroll
        for (int r3 = 0; r3 < 16; ++r3)
            s += c2[((r2 * 8 + n3) * 8 + m3) * 16 + r3] * c3[(r3 * 8 + n4) * 8 + m4];
        ws[65536 + id2] = f2bf(s);
    }
}

// ---------------- main kernel ----------------
#define XT_S 72      // xt row stride (shorts): 144B, 16B-aligned, +4 banks/row
#define T2_S 1032    // t2t row stride (shorts): 2064B, 16B-aligned, +4 banks/row
#define BUFSH (16 * T2_S)

__global__ __launch_bounds__(256, 2) void tt_main(
    const float* __restrict__ x, const short* __restrict__ ws,
    const float* __restrict__ bias, float* __restrict__ out)
{
    __shared__ short t2t[2 * BUFSH];     // 66048 B: buf0 = even n1, buf1 = odd n1
    __shared__ float psum[2][1024];      // 8192 B: [n1&1][slot(0..3)*256 + L*4 + i]

    const short* cc  = ws;               // [8][128][64]
    const short* c23 = ws + 65536;       // [64][1024]

    const int t = threadIdx.x, w = t >> 6, L = t & 63;
    const int quad = L >> 4, l16 = L & 15;
    const long long b0 = (long long)blockIdx.x * 2;
    const int rh = w >> 1, kh = w & 1;   // stage2 roles; stage01 uses same bits

    short* xt = t2t;                     // overlay on buf0: dead after b01 load

    // ---- build xt (bf16, transposed): wave -> b'=rh, p-range kh*32..+31, u=L
    {
        const float* xb = x + (b0 + rh) * 4096;
        const int pr = kh * 32;
        short* dst = &xt[((rh * 64 + L) * XT_S) + pr];
        #pragma unroll
        for (int g = 0; g < 4; ++g) {
            float f[8];
            #pragma unroll
            for (int j = 0; j < 8; ++j) f[j] = xb[(pr + g * 8 + j) * 64 + L];
            int4 pk;
            pk.x = pk2bf(f[0], f[1]); pk.y = pk2bf(f[2], f[3]);
            pk.z = pk2bf(f[4], f[5]); pk.w = pk2bf(f[6], f[7]);
            *(int4*)(dst + g * 8) = pk;
        }
    }

    // ---- persistent A2 frags (C23): wave (rh,kh) -> rows [32rh,32rh+32),
    //      K-slice [512kh, 512kh+512). a2[rt*16+kt]: row 32rh+16rt+l16,
    //      k = 512kh + kt*32 + quad*8.
    bf16x8 a2[32];
    {
        const short* base = c23 + (32 * rh + l16) * 1024 + 512 * kh + quad * 8;
        #pragma unroll
        for (int rt = 0; rt < 2; ++rt)
            #pragma unroll
            for (int kt = 0; kt < 16; ++kt)
                a2[rt * 16 + kt] = *(const bf16x8*)(base + rt * 16 * 1024 + kt * 32);
    }

    // ---- a1 prefetch (h=0 half of stage01 A): consume -> refill -> consume
    bf16x8 a1pf[4];
    auto pfload = [&](int n1) {
        const short* ab = cc + n1 * 8192 + (rh * 64 + l16) * 64 + quad * 8;
        a1pf[0] = *(const bf16x8*)(ab);              // kt=0, mt2=0
        a1pf[1] = *(const bf16x8*)(ab + 1024);       // kt=0, mt2=1
        a1pf[2] = *(const bf16x8*)(ab + 32);         // kt=1, mt2=0
        a1pf[3] = *(const bf16x8*)(ab + 1024 + 32);  // kt=1, mt2=1
    };
    pfload(0);

    __syncthreads();                     // B1: xt complete

    // ---- persistent B01 frags (x): wave -> (rh, kh); kh picks b'
    bf16x8 b01[8];                       // [kt*4+nt]
    #pragma unroll
    for (int kt = 0; kt < 2; ++kt)
        #pragma unroll
        for (int nt = 0; nt < 4; ++nt)
            b01[kt * 4 + nt] =
                *(const bf16x8*)&xt[(kh * 64 + nt * 16 + l16) * XT_S + kt * 32 + quad * 8];

    __syncthreads();                     // B1b: b01 reads done before xt overwritten

    // ---- stage01 + scatter for one n1 into dstbuf
    auto stage01 = [&](int n1, short* dstbuf) {
        #pragma unroll
        for (int h = 0; h < 2; ++h) {
            bf16x8 a1[4];
            if (h == 0) {
                a1[0] = a1pf[0]; a1[1] = a1pf[1]; a1[2] = a1pf[2]; a1[3] = a1pf[3];
            } else {
                const short* ab = cc + n1 * 8192 + (rh * 64 + 32 + l16) * 64 + quad * 8;
                a1[0] = *(const bf16x8*)(ab);
                a1[1] = *(const bf16x8*)(ab + 1024);
                a1[2] = *(const bf16x8*)(ab + 32);
                a1[3] = *(const bf16x8*)(ab + 1024 + 32);
            }
            f32x4 acc[2][4] = {};
            #pragma unroll
            for (int mt2 = 0; mt2 < 2; ++mt2)
                #pragma unroll
                for (int nt = 0; nt < 4; ++nt) {
                    acc[mt2][nt] = __builtin_amdgcn_mfma_f32_16x16x32_bf16(
                        a1[mt2], b01[nt], acc[mt2][nt], 0, 0, 0);
                    acc[mt2][nt] = __builtin_amdgcn_mfma_f32_16x16x32_bf16(
                        a1[2 + mt2], b01[4 + nt], acc[mt2][nt], 0, 0, 0);
                }
            // scatter (b64 stores, swizzled s keeps i=0..3 contiguous)
            #pragma unroll
            for (int mt2 = 0; mt2 < 2; ++mt2) {
                const int n2 = rh * 4 + h * 2 + mt2;
                #pragma unroll
                for (int nt = 0; nt < 4; ++nt) {
                    const int u  = nt * 16 + l16;        // 0..63
                    const int m3 = u >> 3, m4 = u & 7;
                    const int rblk = (quad * 4 + 4 * (m3 & 1)) & 15;
                    int2 pk;
                    pk.x = pk2bf(acc[mt2][nt][0], acc[mt2][nt][1]);
                    pk.y = pk2bf(acc[mt2][nt][2], acc[mt2][nt][3]);
                    *(int2*)&dstbuf[(kh * 8 + n2) * T2_S + (m3 * 8 + m4) * 16 + rblk] = pk;
                }
            }
        }
    };

    // ---- stage2 partial for n1=k (buf p=k&1): writes foreign tile to psum[p],
    //      returns own tile (rows 16w, col l16).
    auto stage2 = [&](int k) -> f32x4 {
        const int p = k & 1;
        f32x4 d2[4] = {};                // [rt*2 + (kt&1)]
        {
            const short* tb = &t2t[p * BUFSH + l16 * T2_S + kh * 512 + quad * 8];
            #pragma unroll
            for (int kt = 0; kt < 16; kt += 2) {
                bf16x8 bf0 = *(const bf16x8*)(tb + kt * 32);
                bf16x8 bf1 = *(const bf16x8*)(tb + kt * 32 + 32);
                d2[0] = __builtin_amdgcn_mfma_f32_16x16x32_bf16(a2[kt],          bf0, d2[0], 0, 0, 0);
                d2[1] = __builtin_amdgcn_mfma_f32_16x16x32_bf16(a2[kt + 1],      bf1, d2[1], 0, 0, 0);
                d2[2] = __builtin_amdgcn_mfma_f32_16x16x32_bf16(a2[16 + kt],     bf0, d2[2], 0, 0, 0);
                d2[3] = __builtin_amdgcn_mfma_f32_16x16x32_bf16(a2[16 + kt + 1], bf1, d2[3], 0, 0, 0);
            }
        }
        f32x4 dt0, dt1, down, dfor;
        #pragma unroll
        for (int i = 0; i < 4; ++i) { dt0[i] = d2[0][i] + d2[1][i];
                                      dt1[i] = d2[2][i] + d2[3][i]; }
        if (kh == 0) { down = dt0; dfor = dt1; }
        else         { down = dt1; dfor = dt0; }
        *(f32x4*)&psum[p][(rh * 2 + (1 - kh)) * 256 + L * 4] = dfor;
        return down;
    };

    // ---- epilogue for n1=k: add partner partial + bias, store
    auto epi = [&](int k, f32x4 down) {
        const int p = k & 1;
        f32x4 pp = *(const f32x4*)&psum[p][(rh * 2 + kh) * 256 + L * 4];
        const int bp = l16 >> 3, n2 = l16 & 7;
        const int off = k * 512 + n2 * 64 + 16 * w + quad * 4;
        const float4 bv = *(const float4*)(bias + off);
        float4 ov;
        ov.x = down[0] + pp[0] + bv.x;
        ov.y = down[1] + pp[1] + bv.y;
        ov.z = down[2] + pp[2] + bv.z;
        ov.w = down[3] + pp[3] + bv.w;
        *(float4*)(out + (b0 + bp) * 4096 + off) = ov;
    };

    // ---- prologue: fill both buffers (n1=0 -> buf0, n1=1 -> buf1)
    stage01(0, t2t);                     // consumes a1pf(0); safe after B1b
    pfload(1);
    stage01(1, t2t + BUFSH);
    __syncthreads();                     // A0: buf0,buf1 ready

    // ---- paired main loop: 2 n1 per iteration, 2 barriers per iteration
    #pragma unroll 1
    for (int j = 0; j < 8; j += 2) {
        if (j < 6) pfload(j + 2);        // h0 of j+2; hides under the S2 pair

        __builtin_amdgcn_s_setprio(1);
        f32x4 dn0 = stage2(j);           // independent stream 1
        f32x4 dn1 = stage2(j + 1);       // independent stream 2
        __builtin_amdgcn_s_setprio(0);
        __syncthreads();                 // psums ready; both bufs consumed

        epi(j, dn0);                     // stores drain over the next region
        epi(j + 1, dn1);
        if (j < 6) {
            stage01(j + 2, t2t);         // consumes a1pf(j+2)
            pfload(j + 3);               // refill; hides under stage01(j+2)
            stage01(j + 3, t2t + BUFSH); // consumes a1pf(j+3)
            __syncthreads();             // bufs(j+2,j+3) ready; psum reads done
        }
    }
}

extern "C" void kernel_launch(void* const* d_in, const int* in_sizes, int n_in,
                              void* d_out, int out_size, void* d_ws, size_t ws_size,
                              hipStream_t stream) {
    const float* x    = (const float*)d_in[0];
    const float* c0   = (const float*)d_in[1];
    const float* c1   = (const float*)d_in[2];
    const float* c2   = (const float*)d_in[3];
    const float* c3   = (const float*)d_in[4];
    const float* bias = (const float*)d_in[5];
    float* out = (float*)d_out;
    short* ws  = (short*)d_ws;           // 256 KB used: CC (128K) + C23 (128K)

    hipLaunchKernelGGL(tt_pre, dim3(512), dim3(256), 0, stream, c0, c1, c2, c3, ws);
    hipLaunchKernelGGL(tt_main, dim3(4096), dim3(256), 0, stream, x, ws, bias, out);
}